// Round 7
// baseline (128.844 us; speedup 1.0000x reference)
//
#include <hip/hip_runtime.h>

#define N 32768
#define P 8192
#define NBLK (N / 32)            // 1024 blocks; 32 x's per block (one MFMA col-tile)
#define THREADS 512              // 8 waves = 8 P-slices
#define SLICES 8
#define PT (P / 32)              // 256 pattern-tiles of 32
#define TPW (PT / SLICES)        // 32 tiles per wave

// f = log2(e)/(2*sigma^2), sigma^2 = 1.44; per-x |x|^2 cancels in num/den.
#define RBF_F 0.50093577808645257f

typedef float  v2f    __attribute__((ext_vector_type(2)));
typedef float  f32x4  __attribute__((ext_vector_type(4)));
typedef float  f32x16 __attribute__((ext_vector_type(16)));
typedef short  s16x8  __attribute__((ext_vector_type(8)));

static __device__ __forceinline__ float fast_exp2(float x) {
#if __has_builtin(__builtin_amdgcn_exp2f)
    return __builtin_amdgcn_exp2f(x);
#else
    return exp2f(x);
#endif
}

static __device__ __forceinline__ void sbar() {
#if __has_builtin(__builtin_amdgcn_sched_barrier)
    __builtin_amdgcn_sched_barrier(0);
#endif
}

static __device__ __forceinline__ unsigned short f2bf(float f) {   // RN f32->bf16
    unsigned u = __float_as_uint(f);
    u += 0x7FFF + ((u >> 16) & 1);
    return (unsigned short)(u >> 16);
}
static __device__ __forceinline__ float bf2f(unsigned short h) {
    return __uint_as_float((unsigned)h << 16);
}

// Per pattern p: A-frag slots (hi/lo split of 2f*p, pre-scaled x0.5 for the
// duplicate-K-group trick) + weights e2c2=2^(-f|p|^2), w'=w*e2c2 stored in
// D-fragment row order: row(r,g) = (r&3) + 8*(r>>2) + 4*g  (m74/m101 layout).
__global__ void prep_kernel(const float* __restrict__ pat,
                            const float* __restrict__ w2,
                            s16x8* __restrict__ afrag,   // [P]   16 B each
                            float* __restrict__ wperm,   // [PT*2*16]
                            float* __restrict__ eperm) { // [PT*2*16]
    int p = blockIdx.x * blockDim.x + threadIdx.x;
    if (p >= P) return;
    float p0 = pat[2 * p], p1 = pat[2 * p + 1];
    float P0 = 2.0f * RBF_F * p0, P1 = 2.0f * RBF_F * p1;
    unsigned short h0 = f2bf(P0);
    unsigned short l0 = f2bf(P0 - bf2f(h0));
    unsigned short h1 = f2bf(P1);
    unsigned short l1 = f2bf(P1 - bf2f(h1));
    // exact halve (exponent decrement via re-round of value*0.5)
    unsigned short H0 = f2bf(bf2f(h0) * 0.5f), L0 = f2bf(bf2f(l0) * 0.5f);
    unsigned short H1 = f2bf(bf2f(h1) * 0.5f), L1 = f2bf(bf2f(l1) * 0.5f);
    // pairs with B(x) slots [xh0, xl0, xh0, xh1, xl1, xh1, 0, 0]:
    //   hi*hi + hi*lo + lo*hi per component
    s16x8 a;
    a[0] = (short)H0; a[1] = (short)H0; a[2] = (short)L0;
    a[3] = (short)H1; a[4] = (short)H1; a[5] = (short)L1;
    a[6] = 0;         a[7] = 0;
    int tile = p >> 5, row = p & 31;
    afrag[tile * 32 + row] = a;

    float c2 = -RBF_F * (p0 * p0 + p1 * p1);
    float e  = exp2f(c2);
    float wp = w2[p] * e;
    int g = (row >> 2) & 1;
    int r = (row & 3) | (((row >> 3) & 3) << 2);
    wperm[(tile * 2 + g) * 16 + r] = wp;
    eperm[(tile * 2 + g) * 16 + r] = e;
}

#define MFMA(A, B, C) __builtin_amdgcn_mfma_f32_32x32x16_bf16((A), (B), (C), 0, 0, 0)

#define EXP16(D)                                                              \
    _Pragma("unroll")                                                         \
    for (int i_ = 0; i_ < 16; ++i_) (D)[i_] = fast_exp2((D)[i_]);

// accumulate 4 k's (D[base..base+3]) against weight quads Wq/Eq via pk_fma
#define ACC4(D, Wq, Eq, base)                                                 \
    den2 = __builtin_elementwise_fma((v2f){(D)[base], (D)[base + 1]},         \
             (v2f){(Eq)[0], (Eq)[1]}, den2);                                  \
    num2 = __builtin_elementwise_fma((v2f){(D)[base], (D)[base + 1]},         \
             (v2f){(Wq)[0], (Wq)[1]}, num2);                                  \
    den2 = __builtin_elementwise_fma((v2f){(D)[base + 2], (D)[base + 3]},     \
             (v2f){(Eq)[2], (Eq)[3]}, den2);                                  \
    num2 = __builtin_elementwise_fma((v2f){(D)[base + 2], (D)[base + 3]},     \
             (v2f){(Wq)[2], (Wq)[3]}, num2);

// Pipeline invariants entering iteration tt (even):
//   D0      = MFMA output of tile tt        (issued one half-iteration ago)
//   Af1     = A-frag of tile tt+1,  Af0 = A-frag of tile tt+2
//   Wa/Ea   = W,E quads of tile tt, Wb/Eb = quads of tile tt+1
// Every load has >= one full tile (~350-700 issue-cycles) before its use.
__global__ __launch_bounds__(THREADS, 2) void
rbf_kernel(const float* __restrict__ X,
           const s16x8* __restrict__ afrag,
           const f32x4* __restrict__ wperm4,
           const f32x4* __restrict__ eperm4,
           float* __restrict__ out) {
    const int t    = threadIdx.x;
    const int lane = t & 63;
    const int wv   = __builtin_amdgcn_readfirstlane(t >> 6);  // slice 0..7
    const int col  = lane & 31;
    const int g    = lane >> 5;

    // B operand (x side), built once: col-th x of this block's 32-x tile
    float2 xv = ((const float2*)X)[blockIdx.x * 32 + col];
    unsigned short xh0 = f2bf(xv.x), xl0 = f2bf(xv.x - bf2f(xh0));
    unsigned short xh1 = f2bf(xv.y), xl1 = f2bf(xv.y - bf2f(xh1));
    s16x8 bx;
    bx[0] = (short)xh0; bx[1] = (short)xl0; bx[2] = (short)xh0;
    bx[3] = (short)xh1; bx[4] = (short)xl1; bx[5] = (short)xh1;
    bx[6] = 0;          bx[7] = 0;

    f32x16 Z;
#pragma unroll
    for (int i = 0; i < 16; ++i) Z[i] = 0.0f;

    const int tile0 = wv * TPW;
    const s16x8* __restrict__ Ap = afrag + tile0 * 32 + col;       // +32/tile
    const f32x4* __restrict__ Wp = wperm4 + (tile0 * 2 + g) * 4;   // +8/tile
    const f32x4* __restrict__ Ep = eperm4 + (tile0 * 2 + g) * 4;

    // prologue: fill the 2-tile software pipeline
    s16x8 Af0 = Ap[0];
    s16x8 Af1 = Ap[32];
    f32x4 Wa0 = Wp[0],  Wa1 = Wp[1],  Wa2 = Wp[2],  Wa3 = Wp[3];
    f32x4 Ea0 = Ep[0],  Ea1 = Ep[1],  Ea2 = Ep[2],  Ea3 = Ep[3];
    f32x4 Wb0 = Wp[8],  Wb1 = Wp[9],  Wb2 = Wp[10], Wb3 = Wp[11];
    f32x4 Eb0 = Ep[8],  Eb1 = Ep[9],  Eb2 = Ep[10], Eb3 = Ep[11];
    f32x16 D0 = MFMA(Af0, bx, Z);     // tile 0
    Af0 = Ap[2 * 32];                 // now holds tile 2
    f32x16 D1;

    v2f num2 = (v2f){0.f, 0.f}, den2 = (v2f){0.f, 0.f};

    for (int tt = 0; tt < TPW; tt += 2) {
        // ---- half A: consume tile tt ----
        D1  = MFMA(Af1, bx, Z);                      // start tile tt+1
        Af1 = Ap[((tt + 3) & (TPW - 1)) * 32];       // A-frag tile tt+3
        EXP16(D0)                                    // 256 cy: covers D1 MFMA + loads
        ACC4(D0, Wa0, Ea0, 0)
        ACC4(D0, Wa1, Ea1, 4)
        ACC4(D0, Wa2, Ea2, 8)
        ACC4(D0, Wa3, Ea3, 12)
        {   // refill even-tile quads with tile tt+2 (used next iter half A)
            const int nq = ((tt + 2) & (TPW - 1)) * 8;
            Wa0 = Wp[nq];     Wa1 = Wp[nq + 1];
            Wa2 = Wp[nq + 2]; Wa3 = Wp[nq + 3];
            Ea0 = Ep[nq];     Ea1 = Ep[nq + 1];
            Ea2 = Ep[nq + 2]; Ea3 = Ep[nq + 3];
        }
        sbar();   // keep half-A loads from sinking into half B
        // ---- half B: consume tile tt+1 ----
        D0  = MFMA(Af0, bx, Z);                      // start tile tt+2
        Af0 = Ap[((tt + 4) & (TPW - 1)) * 32];       // A-frag tile tt+4
        EXP16(D1)
        ACC4(D1, Wb0, Eb0, 0)
        ACC4(D1, Wb1, Eb1, 4)
        ACC4(D1, Wb2, Eb2, 8)
        ACC4(D1, Wb3, Eb3, 12)
        {   // refill odd-tile quads with tile tt+3
            const int nq = ((tt + 3) & (TPW - 1)) * 8;
            Wb0 = Wp[nq];     Wb1 = Wp[nq + 1];
            Wb2 = Wp[nq + 2]; Wb3 = Wp[nq + 3];
            Eb0 = Ep[nq];     Eb1 = Ep[nq + 1];
            Eb2 = Ep[nq + 2]; Eb3 = Ep[nq + 3];
        }
        sbar();
    }

    // epilogue: fold pair, combine the two duplicate row-groups (lane ^ 32),
    // then combine the 8 P-slices via LDS.
    float num = num2.x + num2.y;
    float den = den2.x + den2.y;
    num += __shfl_xor(num, 32, 64);
    den += __shfl_xor(den, 32, 64);

    __shared__ float red[SLICES][32][2];
    if (lane < 32) {
        red[wv][lane][0] = num;
        red[wv][lane][1] = den;
    }
    __syncthreads();

    if (t < 32) {
        float nn = 0.f, dd = 0.f;
#pragma unroll
        for (int s = 0; s < SLICES; ++s) {
            nn += red[s][t][0];
            dd += red[s][t][1];
        }
        out[blockIdx.x * 32 + t] = nn / dd;
    }
}

extern "C" void kernel_launch(void* const* d_in, const int* in_sizes, int n_in,
                              void* d_out, int out_size, void* d_ws, size_t ws_size,
                              hipStream_t stream) {
    const float* X   = (const float*)d_in[0];   // [32768, 2]
    const float* pat = (const float*)d_in[1];   // [8192, 2]
    const float* w2  = (const float*)d_in[2];   // [8192]
    float* out = (float*)d_out;                 // [32768]

    char* ws = (char*)d_ws;                     // 192 KB used
    s16x8* afrag = (s16x8*)ws;                              // 128 KB
    float* wperm = (float*)(ws + (size_t)P * 16);           // 32 KB
    float* eperm = (float*)(ws + (size_t)P * 16 + (size_t)PT * 2 * 16 * 4);

    prep_kernel<<<(P + 255) / 256, 256, 0, stream>>>(pat, w2, afrag, wperm, eperm);
    rbf_kernel<<<NBLK, THREADS, 0, stream>>>(X, afrag,
                                             (const f32x4*)wperm,
                                             (const f32x4*)eperm, out);
}

// Round 8
// 94.877 us; speedup vs baseline: 1.3580x; 1.3580x over previous
//
#include <hip/hip_runtime.h>

#define N 32768
#define P 8192
#define MX 8                          // x-values per wave (wave-uniform)
#define XG 4                          // x-groups per block
#define PH 2                          // pattern halves
#define THREADS (XG * PH * 64)        // 512
#define XPB (XG * MX)                 // 32 x per block
#define NBLK (N / XPB)                // 1024
#define PAIRS (P / 2)                 // 4096 pattern-pairs
#define PAIRS_PER_PH (PAIRS / PH)     // 2048
#define ITERS (PAIRS_PER_PH / 64)     // 32 (power of 2 — wrap prefetch)

// f = log2(e)/(2*sigma^2), sigma^2 = 1.44; per-x |x|^2 cancels in num/den.
#define RBF_F 0.50093577808645257f

typedef float v2f __attribute__((ext_vector_type(2)));

static __device__ __forceinline__ float fast_exp2(float x) {
#if __has_builtin(__builtin_amdgcn_exp2f)
    return __builtin_amdgcn_exp2f(x);
#else
    return exp2f(x);
#endif
}

// Pair-interleaved constants for pattern pair q = (2q, 2q+1):
//   c[2q]   = { c0(2q), c0(2q+1), c1(2q), c1(2q+1) }
//   c[2q+1] = { c2(2q), c2(2q+1), w(2q),  w(2q+1)  }
__global__ void prep_kernel(const float* __restrict__ pat,
                            const float* __restrict__ w2,
                            float4* __restrict__ c) {
    int q = blockIdx.x * blockDim.x + threadIdx.x;
    if (q < P / 2) {
        float p00 = pat[4 * q + 0], p01 = pat[4 * q + 1];
        float p10 = pat[4 * q + 2], p11 = pat[4 * q + 3];
        float4 a, b;
        a.x = 2.0f * RBF_F * p00;  a.y = 2.0f * RBF_F * p10;
        a.z = 2.0f * RBF_F * p01;  a.w = 2.0f * RBF_F * p11;
        b.x = -RBF_F * (p00 * p00 + p01 * p01);
        b.y = -RBF_F * (p10 * p10 + p11 * p11);
        b.z = w2[2 * q];           b.w = w2[2 * q + 1];
        c[2 * q]     = a;
        c[2 * q + 1] = b;
    }
}

// Port-cycle budget per j-body (wave64, SIMD32 datapath, fully serialized):
//   dot    2 v_pk_fma × 8x              =  64 cy
//   accum  (v_pk_add + v_pk_fma) × 8x   =  64 cy
//   exp    16 × v_exp_f32 (4 lanes/cy)  = 256 cy   <- 61%, irreducible
// Measured 45.0 µs = 422 cy/body vs 384 structural floor (7% above).
// Routes eliminated: occupancy 1.7-16 w/SIMD (r2/r5), unroll (r4),
// deeper prefetch (r5), MFMA offload of the dot (r6/r7 — all worse).
#define BODY(aa, bb)                                                          \
    _Pragma("unroll")                                                         \
    for (int i = 0; i < MX; ++i) {                                            \
        v2f tt = __builtin_elementwise_fma((v2f){(aa).x, (aa).y}, xs0[i],     \
                                           (v2f){(bb).x, (bb).y});            \
        tt = __builtin_elementwise_fma((v2f){(aa).z, (aa).w}, xs1[i], tt);    \
        v2f k = (v2f){fast_exp2(tt.x), fast_exp2(tt.y)};                      \
        den2[i] += k;                                                         \
        num2[i] = __builtin_elementwise_fma(k, (v2f){(bb).z, (bb).w},         \
                                            num2[i]);                        \
    }

__global__ __launch_bounds__(THREADS, 4) void
rbf_kernel(const float* __restrict__ X,
           const float4* __restrict__ c,
           float* __restrict__ out) {
    const int t    = threadIdx.x;
    const int lane = t & 63;
    const int w    = __builtin_amdgcn_readfirstlane(t >> 6);  // 0..7
    const int xg   = w >> 1;
    const int ph   = w & 1;

    // MX wave-uniform x-values, hoisted as persistent splat pairs
    const int xb = blockIdx.x * XPB + xg * MX;
    const float2* Xp = (const float2*)X;
    v2f xs0[MX], xs1[MX];
#pragma unroll
    for (int i = 0; i < MX; ++i) {
        float2 xv = Xp[xb + i];
        xs0[i] = (v2f){xv.x, xv.x};
        xs1[i] = (v2f){xv.y, xv.y};
    }

    v2f num2[MX], den2[MX];
#pragma unroll
    for (int i = 0; i < MX; ++i) {
        num2[i] = (v2f){0.f, 0.f};
        den2[i] = (v2f){0.f, 0.f};
    }

    // this wave's pattern-pair stream (L2-resident, coalesced 2 KB/wave/iter)
    const float4* __restrict__ C4 = c + (size_t)ph * (2 * PAIRS_PER_PH);

    // per-block ring-phase desync: blocks start at different table offsets
    const int phase = blockIdx.x & (ITERS - 1);

    // double-buffered, prefetch depth 2, hand-unrolled (no runtime reg idx)
    const int s0 = 2 * (((phase & (ITERS - 1)) << 6) + lane);
    const int s1 = 2 * ((((phase + 1) & (ITERS - 1)) << 6) + lane);
    float4 A0 = C4[s0], B0 = C4[s0 + 1];
    float4 A1 = C4[s1], B1 = C4[s1 + 1];

    for (int j = 0; j < ITERS; j += 2) {
        const int s2 = 2 * ((((phase + j + 2) & (ITERS - 1)) << 6) + lane);
        float4 an = C4[s2], bn = C4[s2 + 1];   // issued ~2 bodies before use
        BODY(A0, B0)
        const int s3 = 2 * ((((phase + j + 3) & (ITERS - 1)) << 6) + lane);
        float4 am = C4[s3], bm = C4[s3 + 1];
        BODY(A1, B1)
        A0 = an; B0 = bn;
        A1 = am; B1 = bm;
    }

    // fold pattern-pair halves, then 6-step butterfly across the wave
    float num[MX], den[MX];
#pragma unroll
    for (int i = 0; i < MX; ++i) {
        num[i] = num2[i].x + num2[i].y;
        den[i] = den2[i].x + den2[i].y;
    }
#pragma unroll
    for (int m = 1; m < 64; m <<= 1) {
#pragma unroll
        for (int i = 0; i < MX; ++i) {
            num[i] += __shfl_xor(num[i], m, 64);
            den[i] += __shfl_xor(den[i], m, 64);
        }
    }

    __shared__ float red[XG][PH][MX][2];
    if (lane == 0) {
#pragma unroll
        for (int i = 0; i < MX; ++i) {
            red[xg][ph][i][0] = num[i];
            red[xg][ph][i][1] = den[i];
        }
    }
    __syncthreads();

    if (t < XPB) {
        int g = t >> 3, xi = t & 7;   // t / MX, t % MX (MX=8)
        float nn = red[g][0][xi][0] + red[g][1][xi][0];
        float dd = red[g][0][xi][1] + red[g][1][xi][1];
        out[blockIdx.x * XPB + t] = nn / dd;
    }
}

extern "C" void kernel_launch(void* const* d_in, const int* in_sizes, int n_in,
                              void* d_out, int out_size, void* d_ws, size_t ws_size,
                              hipStream_t stream) {
    const float* X   = (const float*)d_in[0];   // [32768, 2]
    const float* pat = (const float*)d_in[1];   // [8192, 2]
    const float* w2  = (const float*)d_in[2];   // [8192]
    float* out = (float*)d_out;                 // [32768]
    float4* c = (float4*)d_ws;                  // 8192 * 16 B = 128 KB

    prep_kernel<<<(P / 2 + 255) / 256, 256, 0, stream>>>(pat, w2, c);
    rbf_kernel<<<NBLK, THREADS, 0, stream>>>(X, c, out);
}